// Round 6
// baseline (645.978 us; speedup 1.0000x reference)
//
#include <hip/hip_runtime.h>

// C2SModel: leaf segment-sums + bi-LSTM over paths + fc/tanh
// + segment softmax attention + output GEMM.  All heavy matmuls in bf16 MFMA.
// R6 = R5 with the h-exchange cross-wave overlap fixed (2 KB per wave, was 1 KB).

#define N_CTX_ 65536
#define B_     512
#define E_     128
#define H_     128
#define T_     9
#define DEC_   320
#define OUT_   10000
#define L_     (N_CTX_*5)

typedef __bf16 bf16;
typedef __bf16 bf16x8 __attribute__((ext_vector_type(8)));
typedef __bf16 bf16x4 __attribute__((ext_vector_type(4)));
typedef float  f32x4  __attribute__((ext_vector_type(4)));
typedef float  f32x2  __attribute__((ext_vector_type(2)));
typedef float  f32x16 __attribute__((ext_vector_type(16)));
typedef __fp16 f16x2  __attribute__((ext_vector_type(2)));
typedef unsigned int u32;

__device__ __forceinline__ float fast_tanh(float x){
  float e = __builtin_amdgcn_exp2f(x * -2.8853900817779268f);
  return 2.0f * __builtin_amdgcn_rcpf(1.0f + e) - 1.0f;
}
__device__ __forceinline__ int lbound(const int* __restrict__ a, int n, int key){
  int lo = 0, hi = n;
  while (lo < hi){ int mid = (lo + hi) >> 1; if (a[mid] < key) lo = mid + 1; else hi = mid; }
  return lo;
}
__device__ __forceinline__ u32 cvtpk_bf16(float a, float b){
  u32 d; asm("v_cvt_pk_bf16_f32 %0, %1, %2" : "=v"(d) : "v"(a), "v"(b)); return d;
}
__device__ __forceinline__ float bflo(u32 w){ return __uint_as_float(w << 16); }
__device__ __forceinline__ float bfhi(u32 w){ return __uint_as_float(w & 0xffff0000u); }

// ---- packed f32 helpers -----------------------------------------------------
__device__ __forceinline__ f32x2 pkmul(f32x2 a, f32x2 b){
  f32x2 d; asm("v_pk_mul_f32 %0, %1, %2" : "=v"(d) : "v"(a), "v"(b)); return d;
}
__device__ __forceinline__ f32x2 pkfma(f32x2 a, f32x2 b, f32x2 c){
  f32x2 d; asm("v_pk_fma_f32 %0, %1, %2, %3" : "=v"(d) : "v"(a), "v"(b), "v"(c)); return d;
}
__device__ __forceinline__ f32x2 pkfma_s(f32x2 a, f32x2 b, f32x2 c){
  f32x2 d; asm("v_pk_fma_f32 %0, %1, %2, %3" : "=v"(d) : "v"(a), "v"(b), "s"(c)); return d;
}
// sigmoid ~ 0.5 + x*(s0 + s1 t + s2 t^2 + s3 t^3), t=x^2
__device__ __forceinline__ f32x4 sig4(f32x4 x){
  const f32x2 S3v = {-2.1081349e-4f, -2.1081349e-4f};
  const f32x2 S2  = { 2.0833333e-3f,  2.0833333e-3f};
  const f32x2 S1  = {-2.0833333e-2f, -2.0833333e-2f};
  const f32x2 S0  = { 0.25f, 0.25f};
  const f32x2 HF  = { 0.5f, 0.5f};
  f32x2 xl = {x[0], x[1]}, xh = {x[2], x[3]};
  f32x2 tl = pkmul(xl, xl), th = pkmul(xh, xh);
  f32x2 pl = pkfma_s(tl, S3v, S2), ph = pkfma_s(th, S3v, S2);
  pl = pkfma_s(pl, tl, S1); ph = pkfma_s(ph, th, S1);
  pl = pkfma_s(pl, tl, S0); ph = pkfma_s(ph, th, S0);
  pl = pkfma_s(xl, pl, HF); ph = pkfma_s(xh, ph, HF);
  return f32x4{pl[0], pl[1], ph[0], ph[1]};
}
// tanh ~ x*(c0 + c1 t + ... + c4 t^4)
__device__ __forceinline__ f32x4 tanh4(f32x4 x){
  const f32x2 C4v = { 0.021869489f,  0.021869489f};
  const f32x2 C3  = {-0.053968254f, -0.053968254f};
  const f32x2 C2  = { 0.13333333f,   0.13333333f};
  const f32x2 C1  = {-0.33333333f,  -0.33333333f};
  const f32x2 C0  = { 1.0f, 1.0f};
  f32x2 xl = {x[0], x[1]}, xh = {x[2], x[3]};
  f32x2 tl = pkmul(xl, xl), th = pkmul(xh, xh);
  f32x2 pl = pkfma_s(tl, C4v, C3), ph = pkfma_s(th, C4v, C3);
  pl = pkfma_s(pl, tl, C2); ph = pkfma_s(ph, th, C2);
  pl = pkfma_s(pl, tl, C1); ph = pkfma_s(ph, th, C1);
  pl = pkfma_s(pl, tl, C0); ph = pkfma_s(ph, th, C0);
  pl = pkmul(xl, pl); ph = pkmul(xh, ph);
  return f32x4{pl[0], pl[1], ph[0], ph[1]};
}
__device__ __forceinline__ f32x4 mul4(f32x4 a, f32x4 b){
  f32x2 l = pkmul(f32x2{a[0],a[1]}, f32x2{b[0],b[1]});
  f32x2 h = pkmul(f32x2{a[2],a[3]}, f32x2{b[2],b[3]});
  return f32x4{l[0], l[1], h[0], h[1]};
}
__device__ __forceinline__ f32x4 fma4(f32x4 a, f32x4 b, f32x4 c){
  f32x2 l = pkfma(f32x2{a[0],a[1]}, f32x2{b[0],b[1]}, f32x2{c[0],c[1]});
  f32x2 h = pkfma(f32x2{a[2],a[3]}, f32x2{b[2],b[3]}, f32x2{c[2],c[3]});
  return f32x4{l[0], l[1], h[0], h[1]};
}

// ---- P7 tables: P[node][j] = node_emb@w_ih^T + b_ih + b_hh, bf16, stored so
// lane (lo5,hi1) reads its 32x32x16-D-layout values as two b128s per (slot,nt)
__global__ __launch_bounds__(256) void k_pf(
    const float* __restrict__ nemb,
    const float* __restrict__ wihf, const float* __restrict__ bihf, const float* __restrict__ bhhf,
    const float* __restrict__ wihb, const float* __restrict__ bihb, const float* __restrict__ bhhb,
    bf16* __restrict__ Pf7, bf16* __restrict__ Pb7)
{
  const int node = blockIdx.x, dir = blockIdx.y;
  const float* wih = dir ? wihb : wihf;
  const float* bi  = dir ? bihb : bihf;
  const float* bh  = dir ? bhhb : bhhf;
  bf16* P = dir ? Pb7 : Pf7;
  __shared__ float x[128];
  if (threadIdx.x < 128) x[threadIdx.x] = nemb[node*128 + threadIdx.x];
  __syncthreads();
  const float4* x4 = (const float4*)x;
  #pragma unroll
  for (int jj = 0; jj < 2; ++jj){
    int j = threadIdx.x + jj*256;
    const float4* w4 = (const float4*)(wih + j*128);
    float acc = bi[j] + bh[j];
    #pragma unroll
    for (int k = 0; k < 32; ++k){
      float4 a = w4[k], b = x4[k];
      acc += a.x*b.x + a.y*b.y + a.z*b.z + a.w*b.w;
    }
    int gate = j >> 7, jl7 = j & 127;
    int slot = (gate < 2) ? (1 - gate) : gate;      // f,i,g,o
    int nt = jl7 >> 5, jl = jl7 & 31;
    int q = (jl >> 3) & 3, h1 = (jl >> 2) & 1, r = jl & 3;
    P[(size_t)node*512 + slot*128 + nt*32 + h1*16 + q*4 + r] = (bf16)acc;
  }
}

// ---- weight/table conversions f32 -> bf16; whh gets slot-reorder + LDS-swizzle
__global__ __launch_bounds__(256) void k_cvt(
    const float* __restrict__ fcw, const float* __restrict__ outw,
    const float* __restrict__ whhf, const float* __restrict__ whhb_,
    const float* __restrict__ semb,
    bf16* __restrict__ fcwb, bf16* __restrict__ outwb,
    bf16* __restrict__ whhfS, bf16* __restrict__ whhbS, bf16* __restrict__ sembb)
{
  size_t i = ((size_t)blockIdx.x*256 + threadIdx.x) * 4;
  const float* src; bf16* dst; size_t off; bool scat = false;
  if      (i < 163840)              { src = fcw;   dst = fcwb;  off = i; }
  else if (i < 3363840)             { src = outw;  dst = outwb; off = i - 163840; }
  else if (i < 3429376)             { src = whhf;  dst = whhfS; off = i - 3363840; scat = true; }
  else if (i < 3494912)             { src = whhb_; dst = whhbS; off = i - 3429376; scat = true; }
  else                              { src = semb;  dst = sembb; off = i - 3494912; }
  float4 v = *(const float4*)(src + off);
  bf16x4 o; o[0]=(bf16)v.x; o[1]=(bf16)v.y; o[2]=(bf16)v.z; o[3]=(bf16)v.w;
  size_t d = off;
  if (scat){
    int row = (int)(off >> 7), col = (int)(off & 127);
    int gate = row >> 7, rr = row & 127;
    int slot = (gate < 2) ? (1 - gate) : gate;
    int jrow = slot*128 + rr;
    int cch = col >> 3, jj = col & 7;
    d = (size_t)jrow*128 + ((cch ^ (jrow & 15)) << 3) + jj;
  }
  *(bf16x4*)(dst + d) = o;
}

// ---- segment start tables from sorted index arrays --------------------------
__global__ __launch_bounds__(256) void k_bounds(
    const int* __restrict__ lli, const int* __restrict__ rli,
    int* __restrict__ startL, int* __restrict__ startR)
{
  const int* si = blockIdx.y ? rli : lli;
  int* st = blockIdx.y ? startR : startL;
  int p = blockIdx.x*256 + threadIdx.x;
  if (p > L_) return;
  int cur = (p < L_) ? si[p] : N_CTX_;
  int prv = (p > 0) ? si[p-1] : -1;
  for (int c = prv + 1; c <= cur; ++c) st[c] = p;
}

// ---- leaf segment sums ------------------------------------------------------
__global__ __launch_bounds__(256) void k_leaf(
    const int* __restrict__ lls, const int* __restrict__ rls,
    const int* __restrict__ startL, const int* __restrict__ startR,
    const bf16* __restrict__ sembb, bf16* __restrict__ ctx_in)
{
  int u = blockIdx.x*4 + (threadIdx.x >> 6);
  int lane = threadIdx.x & 63;
  int ctx = u >> 1, side = u & 1;
  const int* st  = side ? rls    : lls;
  const int* stt = side ? startR : startL;
  int a = stt[ctx], b = stt[ctx+1];
  float a0 = 0.f, a1 = 0.f;
  for (int p = a; p < b; ++p){
    unsigned w = *(const unsigned*)&sembb[(size_t)st[p]*128 + lane*2];
    a0 += __uint_as_float(w << 16);
    a1 += __uint_as_float(w & 0xffff0000u);
  }
  *(unsigned*)&ctx_in[(size_t)ctx*512 + (side ? 384 : 0) + lane*2] = cvtpk_bf16(a0, a1);
}

// ---- fused bi-LSTM: transposed 32x32x16 scheme ------------------------------
// G = whh_slot . h^T : A-frag = whh (LDS, pre-swizzled), B-frag = h (regs).
// D: lane holds j = nt*32 + (reg&3) + 8*(reg>>2) + 4*hi1, ctx = lo5.
__global__ __launch_bounds__(512, 2) void k_lstm(
    const int* __restrict__ paths,
    const bf16* __restrict__ whhfS, const bf16* __restrict__ whhbS,
    const bf16* __restrict__ Pf7,   const bf16* __restrict__ Pb7,
    bf16* __restrict__ ctx_in)
{
  const int dir = blockIdx.y;
  const bf16* __restrict__ whhS = dir ? whhbS : whhfS;
  const bf16* __restrict__ P7   = dir ? Pb7   : Pf7;
  __shared__ __align__(16) bf16 whh[512*128];   // 128 KB, pre-swizzled
  __shared__ __align__(16) bf16 hlds[8*1024];   // 8 waves x 2 KB exchange
  const int tid = threadIdx.x, lane = tid & 63, wid = tid >> 6;
  const int lo5 = lane & 31, hi1 = lane >> 5;

  { // stage whh (pure linear copy; swizzle baked into whhS)
    const uint4* s4 = (const uint4*)whhS;
    uint4* d4 = (uint4*)whh;
    #pragma unroll
    for (int it = 0; it < 16; ++it) d4[tid + it*512] = s4[tid + it*512];
  }
  __syncthreads();

  char* __restrict__ hb = (char*)&hlds[wid*1024];  // 2 KB per wave (32 ctx x 64 B)
  const int myctx = blockIdx.x*256 + wid*32 + lo5;
  const int swz = ((lo5 >> 1) & 3) << 4;
  const int wsel = lo5 & 15;

  f32x16 c[4];
  bf16x8 bfr[8];
  #pragma unroll
  for (int n = 0; n < 4; ++n) c[n] = f32x16{};
  #pragma unroll
  for (int k = 0; k < 8; ++k) bfr[k] = bf16x8{};

  int nd = paths[myctx*T_ + (dir ? (T_-1) : 0)];

  #pragma unroll 1
  for (int s = 0; s < T_; ++s){
    const int ndn = (s+1 < T_) ? paths[myctx*T_ + (dir ? (T_-2-s) : (s+1))] : 0;
    const bf16* __restrict__ Pp = P7 + ((size_t)nd << 9) + hi1*16;

    f16x2 iact[4][8];

    #pragma unroll
    for (int slot = 0; slot < 4; ++slot){
      // P gathers (consumed after the MFMA block)
      bf16x8 pv[4][2];
      #pragma unroll
      for (int n = 0; n < 4; ++n){
        pv[n][0] = *(const bf16x8*)(Pp + slot*128 + n*32);
        pv[n][1] = *(const bf16x8*)(Pp + slot*128 + n*32 + 8);
      }
      f32x16 acc[4];
      #pragma unroll
      for (int n = 0; n < 4; ++n) acc[n] = f32x16{};
      #pragma unroll
      for (int kk = 0; kk < 8; ++kk){
        #pragma unroll
        for (int n = 0; n < 4; ++n){
          bf16x8 a = *(const bf16x8*)&whh[(size_t)(slot*128 + n*32 + lo5)*128
                        + (((kk*2 + hi1) ^ wsel) << 3)];
          acc[n] = __builtin_amdgcn_mfma_f32_32x32x16_bf16(a, bfr[kk], acc[n], 0,0,0);
        }
      }
      // add input projection (register-order exact)
      #pragma unroll
      for (int n = 0; n < 4; ++n){
        const u32* w0 = (const u32*)&pv[n][0];
        const u32* w1 = (const u32*)&pv[n][1];
        #pragma unroll
        for (int t = 0; t < 4; ++t){
          acc[n][t*2+0]   += bflo(w0[t]);
          acc[n][t*2+1]   += bfhi(w0[t]);
          acc[n][8+t*2+0] += bflo(w1[t]);
          acc[n][8+t*2+1] += bfhi(w1[t]);
        }
      }

      if (slot == 0){            // forget
        #pragma unroll
        for (int n = 0; n < 4; ++n)
        #pragma unroll
        for (int q = 0; q < 4; ++q){
          f32x4 x = {acc[n][q*4], acc[n][q*4+1], acc[n][q*4+2], acc[n][q*4+3]};
          f32x4 cv = {c[n][q*4], c[n][q*4+1], c[n][q*4+2], c[n][q*4+3]};
          f32x4 r = mul4(sig4(x), cv);
          c[n][q*4]=r[0]; c[n][q*4+1]=r[1]; c[n][q*4+2]=r[2]; c[n][q*4+3]=r[3];
        }
      } else if (slot == 1){     // input
        #pragma unroll
        for (int n = 0; n < 4; ++n)
        #pragma unroll
        for (int q = 0; q < 4; ++q){
          f32x4 x = {acc[n][q*4], acc[n][q*4+1], acc[n][q*4+2], acc[n][q*4+3]};
          f32x4 sv = sig4(x);
          iact[n][q*2]   = __builtin_amdgcn_cvt_pkrtz(sv[0], sv[1]);
          iact[n][q*2+1] = __builtin_amdgcn_cvt_pkrtz(sv[2], sv[3]);
        }
      } else if (slot == 2){     // cell candidate
        #pragma unroll
        for (int n = 0; n < 4; ++n)
        #pragma unroll
        for (int q = 0; q < 4; ++q){
          f32x4 x = {acc[n][q*4], acc[n][q*4+1], acc[n][q*4+2], acc[n][q*4+3]};
          f32x4 cv = {c[n][q*4], c[n][q*4+1], c[n][q*4+2], c[n][q*4+3]};
          f32x4 ia = {(float)iact[n][q*2][0], (float)iact[n][q*2][1],
                      (float)iact[n][q*2+1][0], (float)iact[n][q*2+1][1]};
          f32x4 r = fma4(ia, tanh4(x), cv);
          c[n][q*4]=r[0]; c[n][q*4+1]=r[1]; c[n][q*4+2]=r[2]; c[n][q*4+3]=r[3];
        }
      } else {                   // output -> h, exchange through LDS per n-phase
        #pragma unroll
        for (int n = 0; n < 4; ++n){
          #pragma unroll
          for (int q = 0; q < 4; ++q){
            f32x4 x = {acc[n][q*4], acc[n][q*4+1], acc[n][q*4+2], acc[n][q*4+3]};
            f32x4 cv = {c[n][q*4], c[n][q*4+1], c[n][q*4+2], c[n][q*4+3]};
            f32x4 h = mul4(sig4(x), tanh4(cv));
            uint2 pk = { cvtpk_bf16(h[0], h[1]), cvtpk_bf16(h[2], h[3]) };
            *(uint2*)(hb + lo5*64 + (((q*16 + hi1*8)) ^ swz)) = pk;
          }
          bfr[2*n]   = *(const bf16x8*)(hb + lo5*64 + (((0*32 + hi1*16)) ^ swz));
          bfr[2*n+1] = *(const bf16x8*)(hb + lo5*64 + (((1*32 + hi1*16)) ^ swz));
        }
      }
    }
    nd = ndn;
  }
  // final h: bfr holds h[myctx][k] contiguous -> coalesced b128 stores
  #pragma unroll
  for (int kk = 0; kk < 8; ++kk)
    *(bf16x8*)&ctx_in[(size_t)myctx*512 + 128 + dir*128 + kk*16 + hi1*8] = bfr[kk];
}

// ---- fc: ctx = tanh(ctx_in @ fc_w^T), score = ctx . a; LDS-staged output ----
__global__ __launch_bounds__(256, 2) void k_fc(
    const bf16* __restrict__ ctx_in, const bf16* __restrict__ fcwb,
    const float* __restrict__ avec, bf16* __restrict__ ctxb, float* __restrict__ score)
{
  __shared__ __align__(16) bf16 bsl[320*32];
  __shared__ __align__(16) bf16 obuf[4][16][336];   // +16 pad
  const int tid = threadIdx.x, lane = tid & 63, wid = tid >> 6;
  const int lo4 = lane & 15, hi4 = lane >> 4;
  const int rowbase = blockIdx.x*64 + wid*16;
  bf16x8 afr[16];
  #pragma unroll
  for (int kk = 0; kk < 16; ++kk)
    afr[kk] = *(const bf16x8*)&ctx_in[(size_t)(rowbase + lo4)*512 + kk*32 + hi4*8];
  f32x4 acc[20];
  #pragma unroll
  for (int nt = 0; nt < 20; ++nt) acc[nt] = f32x4{0.f,0.f,0.f,0.f};
  #pragma unroll
  for (int kk = 0; kk < 16; ++kk){
    __syncthreads();
    #pragma unroll
    for (int i = 0; i < 5; ++i){
      int cc = tid + i*256;
      int row = cc >> 2, cg = (cc & 3) << 3;
      *(bf16x8*)&bsl[row*32 + (cg ^ ((row & 3) << 3))] =
          *(const bf16x8*)&fcwb[(size_t)row*512 + kk*32 + cg];
    }
    __syncthreads();
    #pragma unroll
    for (int nt = 0; nt < 20; ++nt){
      int row = nt*16 + lo4;
      bf16x8 b = *(const bf16x8*)&bsl[row*32 + ((hi4*8) ^ ((row & 3) << 3))];
      acc[nt] = __builtin_amdgcn_mfma_f32_16x16x32_bf16(afr[kk], b, acc[nt], 0,0,0);
    }
  }
  float sc[4] = {0.f,0.f,0.f,0.f};
  #pragma unroll
  for (int nt = 0; nt < 20; ++nt){
    float av = avec[nt*16 + lo4];
    #pragma unroll
    for (int r = 0; r < 4; ++r){
      float t = fast_tanh(acc[nt][r]);
      obuf[wid][hi4*4 + r][nt*16 + lo4] = (bf16)t;
      sc[r] += t * av;
    }
  }
  #pragma unroll
  for (int r = 0; r < 4; ++r){
    #pragma unroll
    for (int o = 1; o < 16; o <<= 1) sc[r] += __shfl_xor(sc[r], o, 64);
  }
  if (lo4 == 0){
    #pragma unroll
    for (int r = 0; r < 4; ++r) score[rowbase + hi4*4 + r] = sc[r];
  }
  // coalesced output: lane (lo4=row, hi4): chunks hi4+4k of 8 elems
  #pragma unroll
  for (int k = 0; k < 10; ++k){
    bf16x8 v = *(const bf16x8*)&obuf[wid][lo4][(hi4 + 4*k)*8];
    *(bf16x8*)&ctxb[(size_t)(rowbase + lo4)*320 + (hi4 + 4*k)*8] = v;
  }
}

// ---- segment softmax attention ----------------------------------------------
__global__ __launch_bounds__(320) void k_attn(
    const int* __restrict__ sidx, const float* __restrict__ score,
    const bf16* __restrict__ ctxb, bf16* __restrict__ vb)
{
  const int b = blockIdx.x, tid = threadIdx.x;
  const int lane = tid & 63, wid = tid >> 6;
  const int lo = lbound(sidx, N_CTX_, b);
  const int hi = lbound(sidx, N_CTX_, b + 1);
  __shared__ float red[16];
  float m = -3.0e38f;
  for (int p = lo + tid; p < hi; p += 320) m = fmaxf(m, score[p]);
  #pragma unroll
  for (int o = 1; o < 64; o <<= 1) m = fmaxf(m, __shfl_xor(m, o, 64));
  if (lane == 0) red[wid] = m;
  __syncthreads();
  m = red[0];
  #pragma unroll
  for (int w = 1; w < 5; ++w) m = fmaxf(m, red[w]);
  float sp = 0.f;
  for (int p = lo + tid; p < hi; p += 320)
    sp += __builtin_amdgcn_exp2f((score[p] - m) * 1.4426950408889634f);
  #pragma unroll
  for (int o = 1; o < 64; o <<= 1) sp += __shfl_xor(sp, o, 64);
  __syncthreads();
  if (lane == 0) red[8 + wid] = sp;
  __syncthreads();
  float ssum = red[8] + red[9] + red[10] + red[11] + red[12];
  float inv = __builtin_amdgcn_rcpf(ssum);
  const float K2 = 1.4426950408889634f;
  float v = 0.f;
  int p = lo;
  #pragma unroll 1
  for (; p + 4 <= hi; p += 4){
    float s0 = score[p], s1 = score[p+1], s2 = score[p+2], s3 = score[p+3];
    float c0 = (float)ctxb[(size_t)p*320 + tid];
    float c1 = (float)ctxb[(size_t)(p+1)*320 + tid];
    float c2 = (float)ctxb[(size_t)(p+2)*320 + tid];
    float c3 = (float)ctxb[(size_t)(p+3)*320 + tid];
    v += __builtin_amdgcn_exp2f((s0-m)*K2)*c0 + __builtin_amdgcn_exp2f((s1-m)*K2)*c1
       + __builtin_amdgcn_exp2f((s2-m)*K2)*c2 + __builtin_amdgcn_exp2f((s3-m)*K2)*c3;
  }
  for (; p < hi; ++p)
    v += __builtin_amdgcn_exp2f((score[p]-m)*K2) * (float)ctxb[(size_t)p*320 + tid];
  vb[b*320 + tid] = (hi > lo) ? (bf16)(v * inv) : (bf16)0.f;
}

// ---- output GEMM: out = v @ out_w^T + out_b ----------------------------------
__global__ __launch_bounds__(256, 2) void k_out(
    const bf16* __restrict__ vb, const bf16* __restrict__ outwb,
    const float* __restrict__ outb, float* __restrict__ out)
{
  __shared__ __align__(16) bf16 bsl[256*32];
  const int tid = threadIdx.x, lane = tid & 63, wid = tid >> 6;
  const int lo4 = lane & 15, hi4 = lane >> 4;
  const int ob = blockIdx.x*256;
  const int bb = blockIdx.y*64 + wid*16;
  bf16x8 afr[10];
  #pragma unroll
  for (int kk = 0; kk < 10; ++kk)
    afr[kk] = *(const bf16x8*)&vb[(size_t)(bb + lo4)*320 + kk*32 + hi4*8];
  f32x4 acc[16];
  #pragma unroll
  for (int nt = 0; nt < 16; ++nt) acc[nt] = f32x4{0.f,0.f,0.f,0.f};
  #pragma unroll
  for (int kk = 0; kk < 10; ++kk){
    __syncthreads();
    #pragma unroll
    for (int i = 0; i < 4; ++i){
      int cc = tid + i*256;
      int row = cc >> 2, cg = (cc & 3) << 3;
      int orow = ob + row; if (orow > OUT_ - 1) orow = OUT_ - 1;
      *(bf16x8*)&bsl[row*32 + (cg ^ ((row & 3) << 3))] =
          *(const bf16x8*)&outwb[(size_t)orow*320 + kk*32 + cg];
    }
    __syncthreads();
    #pragma unroll
    for (int nt = 0; nt < 16; ++nt){
      int row = nt*16 + lo4;
      bf16x8 b = *(const bf16x8*)&bsl[row*32 + ((hi4*8) ^ ((row & 3) << 3))];
      acc[nt] = __builtin_amdgcn_mfma_f32_16x16x32_bf16(afr[kk], b, acc[nt], 0,0,0);
    }
  }
  #pragma unroll
  for (int nt = 0; nt < 16; ++nt){
    int o = ob + nt*16 + lo4;
    if (o < OUT_){
      float bias = outb[o];
      #pragma unroll
      for (int r = 0; r < 4; ++r)
        out[(size_t)(bb + hi4*4 + r)*OUT_ + o] = acc[nt][r] + bias;
    }
  }
}

// ---- launch ------------------------------------------------------------------
extern "C" void kernel_launch(void* const* d_in, const int* in_sizes, int n_in,
                              void* d_out, int out_size, void* d_ws, size_t ws_size,
                              hipStream_t stream)
{
  const int*   lls  = (const int*)d_in[0];
  const int*   lli  = (const int*)d_in[1];
  const int*   rls  = (const int*)d_in[2];
  const int*   rli  = (const int*)d_in[3];
  const int*   paths= (const int*)d_in[4];
  const int*   sidx = (const int*)d_in[5];
  const float* semb = (const float*)d_in[6];
  const float* nemb = (const float*)d_in[7];
  const float* wihf = (const float*)d_in[8];
  const float* whhf = (const float*)d_in[9];
  const float* bihf = (const float*)d_in[10];
  const float* bhhf = (const float*)d_in[11];
  const float* wihb = (const float*)d_in[12];
  const float* whhb = (const float*)d_in[13];
  const float* bihb = (const float*)d_in[14];
  const float* bhhb = (const float*)d_in[15];
  const float* fcw  = (const float*)d_in[16];
  const float* avec = (const float*)d_in[17];
  const float* outw = (const float*)d_in[18];
  const float* outb = (const float*)d_in[19];
  float* out = (float*)d_out;

  char* w = (char*)d_ws;
  bf16*  Pf7   = (bf16*)w;  w += (size_t)512*512*2;
  bf16*  Pb7   = (bf16*)w;  w += (size_t)512*512*2;
  bf16*  ctx_in= (bf16*)w;  w += (size_t)N_CTX_*512*2;
  bf16*  ctxb  = (bf16*)w;  w += (size_t)N_CTX_*320*2;
  float* score = (float*)w; w += (size_t)N_CTX_*4;
  bf16*  vb    = (bf16*)w;  w += (size_t)512*320*2;
  bf16*  fcwb  = (bf16*)w;  w += (size_t)320*512*2;
  bf16*  outwb = (bf16*)w;  w += (size_t)OUT_*320*2;
  bf16*  whhfS = (bf16*)w;  w += (size_t)512*128*2;
  bf16*  whhbS = (bf16*)w;  w += (size_t)512*128*2;
  bf16*  sembb = (bf16*)w;  w += (size_t)50000*128*2;
  int*   startL= (int*)w;   w += (size_t)(N_CTX_+16)*4;
  int*   startR= (int*)w;   w += (size_t)(N_CTX_+16)*4;

  k_pf    <<<dim3(512, 2), 256, 0, stream>>>(nemb, wihf, bihf, bhhf, wihb, bihb, bhhb, Pf7, Pb7);
  k_cvt   <<<dim3(9663), 256, 0, stream>>>(fcw, outw, whhf, whhb, semb,
                                           fcwb, outwb, whhfS, whhbS, sembb);
  k_bounds<<<dim3((L_ + 256)/256 + 1, 2), 256, 0, stream>>>(lli, rli, startL, startR);
  k_leaf  <<<dim3(N_CTX_*2/4), 256, 0, stream>>>(lls, rls, startL, startR, sembb, ctx_in);
  k_lstm  <<<dim3(256, 2), 512, 0, stream>>>(paths, whhfS, whhbS, Pf7, Pb7, ctx_in);
  k_fc    <<<dim3(1024), 256, 0, stream>>>(ctx_in, fcwb, avec, ctxb, score);
  k_attn  <<<dim3(512), 320, 0, stream>>>(sidx, score, ctxb, vb);
  k_out   <<<dim3(40, 8), 256, 0, stream>>>(vb, outwb, outb, out);
}